// Round 1
// baseline (4205.618 us; speedup 1.0000x reference)
//
#include <hip/hip_runtime.h>
#include <hip/hip_bf16.h>

// ---------------- problem constants ----------------
constexpr int kB  = 2;
constexpr int kS  = 4096;
constexpr int kT  = 2048;
constexpr int kV  = 32000;
constexpr int kD  = 512;
constexpr int kH  = 8;
constexpr int kDH = 64;
constexpr int kNH = 4;     // n_hashes
constexpr int kNC = 64;    // chunks = S/BUCKET
constexpr int kNB2 = 32;

// ============================================================
// embed: x1[b,s,:] = emb[src[b,s]] + pos_enc[0,s,:]
// ============================================================
__global__ __launch_bounds__(256) void embed_kernel(
    const int* __restrict__ src, const float* __restrict__ emb,
    const float* __restrict__ pos, float* __restrict__ x1)
{
  int i4 = blockIdx.x * 256 + threadIdx.x;       // over B*S*D/4 = 1048576
  int bs = i4 >> 7, r4 = i4 & 127;
  int tok = src[bs];
  int s = bs & (kS - 1);
  float4 e = ((const float4*)emb)[(size_t)tok * 128 + r4];
  float4 p = ((const float4*)pos)[(size_t)s * 128 + r4];
  ((float4*)x1)[i4] = make_float4(e.x + p.x, e.y + p.y, e.z + p.z, e.w + p.w);
}

// ============================================================
// layernorm: out = (x - m) * rsqrt(var + 1e-5) * sc + bi
// one wave per row (4 rows / 256-thread block)
// ============================================================
__global__ __launch_bounds__(256) void ln_kernel(
    const float* __restrict__ x, const float* __restrict__ sc,
    const float* __restrict__ bi, float* __restrict__ out)
{
  int row = blockIdx.x * 4 + (threadIdx.x >> 6);
  int lane = threadIdx.x & 63;
  const float4* xr = (const float4*)(x + (size_t)row * kD);
  float4 v0 = xr[lane], v1 = xr[lane + 64];
  float sum = v0.x + v0.y + v0.z + v0.w + v1.x + v1.y + v1.z + v1.w;
  #pragma unroll
  for (int off = 1; off < 64; off <<= 1) sum += __shfl_xor(sum, off);
  float m = sum * (1.f / kD);
  float4 d0 = make_float4(v0.x - m, v0.y - m, v0.z - m, v0.w - m);
  float4 d1 = make_float4(v1.x - m, v1.y - m, v1.z - m, v1.w - m);
  float vs = d0.x*d0.x + d0.y*d0.y + d0.z*d0.z + d0.w*d0.w
           + d1.x*d1.x + d1.y*d1.y + d1.z*d1.z + d1.w*d1.w;
  #pragma unroll
  for (int off = 1; off < 64; off <<= 1) vs += __shfl_xor(vs, off);
  float rr = rsqrtf(vs * (1.f / kD) + 1e-5f);
  const float4* s4 = (const float4*)sc;
  const float4* b4 = (const float4*)bi;
  float4 s0 = s4[lane], s1 = s4[lane + 64], bb0 = b4[lane], bb1 = b4[lane + 64];
  float4 o0 = make_float4(d0.x*rr*s0.x + bb0.x, d0.y*rr*s0.y + bb0.y,
                          d0.z*rr*s0.z + bb0.z, d0.w*rr*s0.w + bb0.w);
  float4 o1 = make_float4(d1.x*rr*s1.x + bb1.x, d1.y*rr*s1.y + bb1.y,
                          d1.z*rr*s1.z + bb1.z, d1.w*rr*s1.w + bb1.w);
  float4* op = (float4*)(out + (size_t)row * kD);
  op[lane] = o0; op[lane + 64] = o1;
}

// ============================================================
// generic fp32 GEMM: C[m,n] = resid? + sig(gate[n])*act(A@B + bias[n])
// 128x128 tile, BK=16, 256 threads, 8x8 microtile. Dims divide exactly.
// ============================================================
constexpr int GBM = 128, GBN = 128, GBK = 16;

__global__ __launch_bounds__(256) void gemm_f32(
    const float* __restrict__ A, const float* __restrict__ Bw,
    float* __restrict__ C, const float* __restrict__ bias,
    const float* __restrict__ resid, const float* __restrict__ gatev,
    int M, int N, int K, int relu)
{
  __shared__ float As[GBK][GBM];   // transposed: As[k][m]
  __shared__ float Bs[GBK][GBN];
  const int tid = threadIdx.x;
  const int tx = tid & 15, ty = tid >> 4;
  const int n0 = blockIdx.x * GBN, m0 = blockIdx.y * GBM;
  float acc[8][8] = {};
  for (int k0 = 0; k0 < K; k0 += GBK) {
    #pragma unroll
    for (int it = 0; it < 2; ++it) {
      int t = tid + it * 256;
      int row = t >> 2, c4 = (t & 3) << 2;
      float4 a4 = *(const float4*)&A[(size_t)(m0 + row) * K + k0 + c4];
      As[c4 + 0][row] = a4.x; As[c4 + 1][row] = a4.y;
      As[c4 + 2][row] = a4.z; As[c4 + 3][row] = a4.w;
    }
    #pragma unroll
    for (int it = 0; it < 2; ++it) {
      int t = tid + it * 256;
      int row = t >> 5, c4 = (t & 31) << 2;
      *(float4*)&Bs[row][c4] = *(const float4*)&Bw[(size_t)(k0 + row) * N + n0 + c4];
    }
    __syncthreads();
    #pragma unroll
    for (int kk = 0; kk < GBK; ++kk) {
      float4 a0 = *(float4*)&As[kk][ty * 8], a1 = *(float4*)&As[kk][ty * 8 + 4];
      float4 b0 = *(float4*)&Bs[kk][tx * 8], b1 = *(float4*)&Bs[kk][tx * 8 + 4];
      float av[8] = {a0.x, a0.y, a0.z, a0.w, a1.x, a1.y, a1.z, a1.w};
      float bv[8] = {b0.x, b0.y, b0.z, b0.w, b1.x, b1.y, b1.z, b1.w};
      #pragma unroll
      for (int i = 0; i < 8; ++i) {
        #pragma unroll
        for (int j = 0; j < 8; ++j)
          acc[i][j] = fmaf(av[i], bv[j], acc[i][j]);
      }
    }
    __syncthreads();
  }
  #pragma unroll
  for (int i = 0; i < 8; ++i) {
    int m = m0 + ty * 8 + i;
    size_t rowb = (size_t)m * N + n0 + tx * 8;
    #pragma unroll
    for (int j2 = 0; j2 < 2; ++j2) {
      float o[4];
      #pragma unroll
      for (int j = 0; j < 4; ++j) {
        int n = n0 + tx * 8 + j2 * 4 + j;
        float vv = acc[i][j2 * 4 + j];
        if (bias)  vv += bias[n];
        if (relu)  vv = fmaxf(vv, 0.f);
        if (gatev) vv *= 1.f / (1.f + __expf(-gatev[n]));
        if (resid) vv += resid[rowb + j2 * 4 + j];
        o[j] = vv;
      }
      *(float4*)&C[rowb + j2 * 4] = make_float4(o[0], o[1], o[2], o[3]);
    }
  }
}

// ============================================================
// LSH projections + bucket argmax. block = (b,h) x 256 s; hashR staged in LDS.
// buckets layout: ((b*H+h)*NH + r)*S + s
// ============================================================
__global__ __launch_bounds__(256) void lsh_proj_kernel(
    const float* __restrict__ qk, const float* __restrict__ hashRl,
    int* __restrict__ buckets)
{
  __shared__ float shR[kNH * kDH * kNB2];   // 8192 floats
  const int bh = blockIdx.x, b = bh >> 3, h = bh & 7;
  const int tid = threadIdx.x;
  for (int i = tid; i < kNH * kDH * kNB2; i += 256) {
    int r = i >> 11, rem = i & 2047;       // rem = d*32+n
    shR[i] = hashRl[((size_t)(r * kH + h)) * 2048 + rem];
  }
  __syncthreads();
  const int s = blockIdx.y * 256 + tid;
  const float4* q4p = (const float4*)&qk[((size_t)(b * kS + s)) * kD + h * kDH];
  for (int rr = 0; rr < kNH; ++rr) {
    float acc[32] = {};
    const float4* h4 = (const float4*)&shR[rr * 2048];
    for (int d4 = 0; d4 < 16; ++d4) {
      float4 qv4 = q4p[d4];
      float qs[4] = {qv4.x, qv4.y, qv4.z, qv4.w};
      #pragma unroll
      for (int dd = 0; dd < 4; ++dd) {
        const float4* hh = &h4[(d4 * 4 + dd) * 8];
        float qv = qs[dd];
        #pragma unroll
        for (int n4 = 0; n4 < 8; ++n4) {
          float4 hv = hh[n4];
          acc[n4*4+0] = fmaf(qv, hv.x, acc[n4*4+0]);
          acc[n4*4+1] = fmaf(qv, hv.y, acc[n4*4+1]);
          acc[n4*4+2] = fmaf(qv, hv.z, acc[n4*4+2]);
          acc[n4*4+3] = fmaf(qv, hv.w, acc[n4*4+3]);
        }
      }
    }
    // argmax over concat([proj, -proj]) — first max wins (matches jnp.argmax)
    float best = acc[0]; int bi = 0;
    #pragma unroll
    for (int n = 1; n < 32; ++n) { if (acc[n] > best) { best = acc[n]; bi = n; } }
    #pragma unroll
    for (int n = 0; n < 32; ++n) { float t = -acc[n]; if (t > best) { best = t; bi = 32 + n; } }
    buckets[((size_t)(bh * kNH + rr)) * kS + s] = bi;
  }
}

// ============================================================
// stable counting sort by bucket (== argsort(bucket*S+pos)).
// one wave per (b,h,r); 64 buckets.
// ============================================================
__global__ __launch_bounds__(64) void sort_kernel(
    const int* __restrict__ buckets, int* __restrict__ perm)
{
  __shared__ int lb[kS];
  __shared__ int hist[64];
  __shared__ int offs[64];
  const int base = blockIdx.x * kS;
  const int tid = threadIdx.x;
  const int4* b4 = (const int4*)(buckets + base);
  for (int i = tid; i < kS / 4; i += 64) ((int4*)lb)[i] = b4[i];
  hist[tid] = 0;
  __syncthreads();
  for (int i = tid; i < kS; i += 64) atomicAdd(&hist[lb[i]], 1);
  __syncthreads();
  if (tid == 0) {
    int run = 0;
    for (int j = 0; j < 64; ++j) { offs[j] = run; run += hist[j]; }
  }
  __syncthreads();
  int off = offs[tid];                      // thread t owns bucket t; stable scan
  for (int i = 0; i < kS; ++i)
    if (lb[i] == tid) perm[base + off++] = i;
}

// ============================================================
// chunk attention for one hash r. Block = (chunk, b*H). 64q x 128k x 64d.
// Keys = own chunk (rows 0..63) ++ previous chunk (wrap). Accumulates g_out.
// LDS: KT[64][128] (d-major, aliased by Vs[128][64]) + swizzled Ss = 64KB.
// ============================================================
__device__ __forceinline__ int ssw(int q, int k) { return q * 128 + (k ^ (q & 31)); }

__global__ __launch_bounds__(256) void chunk_attn_kernel(
    const float* __restrict__ qk, const float* __restrict__ v,
    const int* __restrict__ perm, float* __restrict__ gout, int r)
{
  __shared__ float sm[16384];
  float* KT = sm;          // phase 1: KT[d*128 + row]
  float* Vs = sm;          // phase 2: Vs[row*64 + dd]
  float* Ss = sm + 8192;   // scores, XOR-swizzled
  const int c = blockIdx.x, bh = blockIdx.y;
  const int b = bh >> 3, h = bh & 7;
  const int tid = threadIdx.x;
  const int permBase = (bh * kNH + r) * kS;

  // stage K (transposed)
  #pragma unroll
  for (int it = 0; it < 8; ++it) {
    int task = tid + it * 256;
    int row = task >> 4, q4 = (task & 15) << 2;
    int srt = (row < 64) ? (c * 64 + row) : (((c + 63) & 63) * 64 + (row - 64));
    int orig = perm[permBase + srt];
    float4 kv = *(const float4*)&qk[((size_t)(b * kS + orig)) * kD + h * kDH + q4];
    KT[(q4 + 0) * 128 + row] = kv.x;
    KT[(q4 + 1) * 128 + row] = kv.y;
    KT[(q4 + 2) * 128 + row] = kv.z;
    KT[(q4 + 3) * 128 + row] = kv.w;
  }
  __syncthreads();

  // scores: thread (tx,ty) -> queries ty*4+i, keys tx*8+j
  const int tx = tid & 15, ty = tid >> 4;
  float accS[4][8] = {};
  #pragma unroll 8
  for (int d = 0; d < 64; ++d) {
    const float* Kd = &KT[d * 128];
    float qv[4];
    #pragma unroll
    for (int i = 0; i < 4; ++i) qv[i] = Kd[ty * 4 + i];
    float4 k0 = *(const float4*)&Kd[tx * 8];
    float4 k1 = *(const float4*)&Kd[tx * 8 + 4];
    float kv[8] = {k0.x, k0.y, k0.z, k0.w, k1.x, k1.y, k1.z, k1.w};
    #pragma unroll
    for (int i = 0; i < 4; ++i) {
      #pragma unroll
      for (int j = 0; j < 8; ++j)
        accS[i][j] = fmaf(qv[i], kv[j], accS[i][j]);
    }
  }
  #pragma unroll
  for (int i = 0; i < 4; ++i) {
    #pragma unroll
    for (int j = 0; j < 8; ++j)
      Ss[ssw(ty * 4 + i, tx * 8 + j)] = accS[i][j] * 0.125f;
  }
  __syncthreads();   // scores visible; KT reads done

  // stage V (overwrites KT region); wave 0 then does softmax
  #pragma unroll
  for (int it = 0; it < 8; ++it) {
    int task = tid + it * 256;
    int row = task >> 4, q4 = (task & 15) << 2;
    int srt = (row < 64) ? (c * 64 + row) : (((c + 63) & 63) * 64 + (row - 64));
    int orig = perm[permBase + srt];
    float4 vv = *(const float4*)&v[((size_t)(b * kS + orig)) * kD + h * kDH + q4];
    *(float4*)&Vs[row * 64 + q4] = vv;
  }
  if (tid < 64) {
    int q = tid, qx = q & 31;
    float mxv = -1e30f;
    for (int k = 0; k < 128; ++k) mxv = fmaxf(mxv, Ss[q * 128 + (k ^ qx)]);
    float se = 0.f;
    for (int k = 0; k < 128; ++k) {
      float e = __expf(Ss[q * 128 + (k ^ qx)] - mxv);
      Ss[q * 128 + (k ^ qx)] = e; se += e;
    }
    float inv = 1.f / se;
    for (int k = 0; k < 128; ++k) Ss[q * 128 + (k ^ qx)] *= inv;
  }
  __syncthreads();

  // PV: thread (tx,ty) -> queries ty*4+i, dims tx*4+j
  float accO[4][4] = {};
  #pragma unroll 8
  for (int k = 0; k < 128; ++k) {
    float pv[4];
    #pragma unroll
    for (int i = 0; i < 4; ++i) pv[i] = Ss[ssw(ty * 4 + i, k)];
    float4 vr = *(const float4*)&Vs[k * 64 + tx * 4];
    float vw[4] = {vr.x, vr.y, vr.z, vr.w};
    #pragma unroll
    for (int i = 0; i < 4; ++i) {
      #pragma unroll
      for (int j = 0; j < 4; ++j)
        accO[i][j] = fmaf(pv[i], vw[j], accO[i][j]);
    }
  }
  // scatter-accumulate to original positions (perm bijective per r -> race-free)
  #pragma unroll
  for (int i = 0; i < 4; ++i) {
    int q = ty * 4 + i;
    int orig = perm[permBase + c * 64 + q];
    float* gp = &gout[((size_t)(bh * kS + orig)) * kDH + tx * 4];
    float4 g4 = *(float4*)gp;
    g4.x += accO[i][0]; g4.y += accO[i][1]; g4.z += accO[i][2]; g4.w += accO[i][3];
    *(float4*)gp = g4;
  }
}

// ============================================================
// local attention (9 offsets) + gate + merge with LSH avg; writes (B,S,D)
// head-concat layout ready for the Wo GEMM. Accumulates reg = sum g(1-g).
// ============================================================
__global__ __launch_bounds__(256) void combine_kernel(
    const float* __restrict__ qk, const float* __restrict__ v,
    const float* __restrict__ gout, const float* __restrict__ gate_w,
    float* __restrict__ o_out, float* __restrict__ reg_acc)
{
  const int bh = blockIdx.x, b = bh >> 3, h = bh & 7;
  const int s = blockIdx.y * 256 + threadIdx.x;
  const float4* qrow = (const float4*)&qk[((size_t)(b * kS + s)) * kD + h * kDH];
  float4 q4[16];
  #pragma unroll
  for (int i = 0; i < 16; ++i) q4[i] = qrow[i];

  const float4* gw4 = (const float4*)&gate_w[h * kDH];
  float gd = 0.f;
  #pragma unroll
  for (int i = 0; i < 16; ++i) {
    float4 g = gw4[i];
    gd += q4[i].x * g.x + q4[i].y * g.y + q4[i].z * g.z + q4[i].w * g.w;
  }
  float gate = 1.f / (1.f + __expf(-gd));

  float p[9]; float mx = -1e30f;
  #pragma unroll
  for (int w = 0; w < 9; ++w) {
    int ss = s + w - 4;
    float scv = -1e9f;
    if (ss >= 0 && ss < kS) {
      const float4* kr = (const float4*)&qk[((size_t)(b * kS + ss)) * kD + h * kDH];
      float a = 0.f;
      #pragma unroll
      for (int i = 0; i < 16; ++i) {
        float4 kk = kr[i];
        a += q4[i].x * kk.x + q4[i].y * kk.y + q4[i].z * kk.z + q4[i].w * kk.w;
      }
      scv = a * 0.125f;
    }
    p[w] = scv; mx = fmaxf(mx, scv);
  }
  float se = 0.f;
  #pragma unroll
  for (int w = 0; w < 9; ++w) { p[w] = __expf(p[w] - mx); se += p[w]; }
  float inv = 1.f / se;

  const float4* g4p = (const float4*)&gout[((size_t)(bh * kS + s)) * kDH];
  float4* op = (float4*)&o_out[((size_t)(b * kS + s)) * kD + h * kDH];
  float og = gate, ol = 1.f - gate;
  #pragma unroll
  for (int d4 = 0; d4 < 16; ++d4) {
    float ax = 0.f, ay = 0.f, az = 0.f, aw = 0.f;
    #pragma unroll
    for (int w = 0; w < 9; ++w) {
      int ss = s + w - 4;
      if (ss >= 0 && ss < kS) {
        const float4* vr = (const float4*)&v[((size_t)(b * kS + ss)) * kD + h * kDH];
        float4 vv = vr[d4];
        ax = fmaf(p[w], vv.x, ax); ay = fmaf(p[w], vv.y, ay);
        az = fmaf(p[w], vv.z, az); aw = fmaf(p[w], vv.w, aw);
      }
    }
    float4 gg = g4p[d4];
    float4 o;
    o.x = og * (gg.x * 0.25f) + ol * (ax * inv);
    o.y = og * (gg.y * 0.25f) + ol * (ay * inv);
    o.z = og * (gg.z * 0.25f) + ol * (az * inv);
    o.w = og * (gg.w * 0.25f) + ol * (aw * inv);
    op[d4] = o;
  }
  // reg reduction
  float rg = gate * (1.f - gate);
  #pragma unroll
  for (int off = 1; off < 64; off <<= 1) rg += __shfl_xor(rg, off);
  __shared__ float wsum[4];
  if ((threadIdx.x & 63) == 0) wsum[threadIdx.x >> 6] = rg;
  __syncthreads();
  if (threadIdx.x == 0) atomicAdd(reg_acc, wsum[0] + wsum[1] + wsum[2] + wsum[3]);
}

// ============================================================
// out = (x1 + x2)/2 for the first T tokens per batch (compact B*T x D)
// ============================================================
__global__ __launch_bounds__(256) void avg_kernel(
    const float* __restrict__ x1, const float* __restrict__ x2,
    float* __restrict__ out)
{
  int i4 = blockIdx.x * 256 + threadIdx.x;   // over B*T*D/4 = 524288
  int bt = i4 >> 7, r4 = i4 & 127;
  int b = bt >> 11, t = bt & (kT - 1);
  size_t si = ((size_t)(b * kS + t)) * 128 + r4;
  float4 a = ((const float4*)x1)[si], c = ((const float4*)x2)[si];
  ((float4*)out)[i4] = make_float4(0.5f * (a.x + c.x), 0.5f * (a.y + c.y),
                                   0.5f * (a.z + c.z), 0.5f * (a.w + c.w));
}

__global__ void finalize_kernel(const float* __restrict__ reg, float* __restrict__ out) {
  if (threadIdx.x == 0) out[0] = reg[0] * (1.f / 65536.f);  // /(B*H*S), both layers summed
}

// ============================================================
extern "C" void kernel_launch(void* const* d_in, const int* in_sizes, int n_in,
                              void* d_out, int out_size, void* d_ws, size_t ws_size,
                              hipStream_t stream)
{
  const int*   src   = (const int*)d_in[0];
  const float* emb   = (const float*)d_in[2];
  const float* pos   = (const float*)d_in[3];
  const float* alns  = (const float*)d_in[4];
  const float* alnb  = (const float*)d_in[5];
  const float* Wqk   = (const float*)d_in[6];
  const float* Wv    = (const float*)d_in[7];
  const float* Wo    = (const float*)d_in[8];
  const float* hashR = (const float*)d_in[9];
  const float* gatew = (const float*)d_in[10];
  const float* rg1   = (const float*)d_in[11];
  const float* rg2   = (const float*)d_in[12];
  const float* flns  = (const float*)d_in[13];
  const float* flnb  = (const float*)d_in[14];
  const float* W1    = (const float*)d_in[15];
  const float* b1    = (const float*)d_in[16];
  const float* W2    = (const float*)d_in[17];
  const float* b2    = (const float*)d_in[18];
  const float* outW  = (const float*)d_in[19];
  const float* outb  = (const float*)d_in[20];
  float* logits = (float*)d_out;

  constexpr size_t NBS = (size_t)kB * kS * kD;   // 4194304 floats
  float* x1 = (float*)d_ws;
  float* x2 = x1 + NBS;
  float* xn = x2 + NBS;
  float* qk = xn + NBS;
  float* vv = qk + NBS;
  float* go = vv + NBS;                          // B*H*S*DH == NBS
  int* buckets = (int*)(go + NBS);
  int* perm    = buckets + (kB * kH * kNH * kS);
  float* reg   = (float*)(perm + (kB * kH * kNH * kS));

  embed_kernel<<<4096, 256, 0, stream>>>(src, emb, pos, x1);
  hipMemsetAsync(x2, 0, NBS * sizeof(float), stream);
  hipMemsetAsync(reg, 0, sizeof(float), stream);

  const dim3 gSmall(kD / GBN, kB * kS / GBM);    // (4, 64)
  for (int l = 0; l < 2; ++l) {
    ln_kernel<<<kB * kS / 4, 256, 0, stream>>>(x2, alns + l * kD, alnb + l * kD, xn);
    gemm_f32<<<gSmall, 256, 0, stream>>>(xn, Wqk + (size_t)l * kD * kD, qk,
                                         nullptr, nullptr, nullptr, kB * kS, kD, kD, 0);
    gemm_f32<<<gSmall, 256, 0, stream>>>(xn, Wv + (size_t)l * kD * kD, vv,
                                         nullptr, nullptr, nullptr, kB * kS, kD, kD, 0);
    lsh_proj_kernel<<<dim3(kB * kH, kS / 256), 256, 0, stream>>>(
        qk, hashR + (size_t)l * kNH * kH * kDH * kNB2, buckets);
    sort_kernel<<<kB * kH * kNH, 64, 0, stream>>>(buckets, perm);
    hipMemsetAsync(go, 0, NBS * sizeof(float), stream);
    for (int r = 0; r < kNH; ++r)
      chunk_attn_kernel<<<dim3(kNC, kB * kH), 256, 0, stream>>>(qk, vv, perm, go, r);
    combine_kernel<<<dim3(kB * kH, kS / 256), 256, 0, stream>>>(
        qk, vv, go, gatew + l * kH * kDH, xn, reg);
    // x1 += sig(rev_g1) * (o @ Wo)
    gemm_f32<<<gSmall, 256, 0, stream>>>(xn, Wo + (size_t)l * kD * kD, x1,
                                         nullptr, x1, rg1 + l * kD, kB * kS, kD, kD, 0);
    ln_kernel<<<kB * kS / 4, 256, 0, stream>>>(x1, flns + l * kD, flnb + l * kD, qk);
    gemm_f32<<<gSmall, 256, 0, stream>>>(qk, W1 + (size_t)l * kD * kD, vv,
                                         b1 + l * kD, nullptr, nullptr, kB * kS, kD, kD, 1);
    // x2 += sig(rev_g2) * (relu(h@W1+b1) @ W2 + b2)
    gemm_f32<<<gSmall, 256, 0, stream>>>(vv, W2 + (size_t)l * kD * kD, x2,
                                         b2 + l * kD, x2, rg2 + l * kD, kB * kS, kD, kD, 0);
  }
  avg_kernel<<<kB * kT * kD / 4 / 256, 256, 0, stream>>>(x1, x2, xn);
  gemm_f32<<<dim3(kV / GBN, kB * kT / GBM), 256, 0, stream>>>(
      xn, outW, logits, outb, nullptr, nullptr, kB * kT, kV, kD, 0);
  finalize_kernel<<<1, 1, 0, stream>>>(reg, logits + (size_t)kB * kT * kV);
}

// Round 3
// 2489.311 us; speedup vs baseline: 1.6895x; 1.6895x over previous
//
#include <hip/hip_runtime.h>
#include <hip/hip_bf16.h>

typedef unsigned short u16;

// ---------------- problem constants ----------------
constexpr int kB  = 2;
constexpr int kS  = 4096;
constexpr int kT  = 2048;
constexpr int kV  = 32000;
constexpr int kD  = 512;
constexpr int kH  = 8;
constexpr int kDH = 64;
constexpr int kNH = 4;     // n_hashes
constexpr int kNC = 64;    // chunks = S/BUCKET
constexpr int kNB2 = 32;

using bf16x8 = __attribute__((ext_vector_type(8))) short;
using f32x4  = __attribute__((ext_vector_type(4))) float;

__device__ __forceinline__ u16 f2bf(float x) {
  union { float f; unsigned u; } v; v.f = x;
  unsigned r = v.u + 0x7fffu + ((v.u >> 16) & 1u);
  return (u16)(r >> 16);
}
__device__ __forceinline__ float bf2f(u16 h) {
  union { unsigned u; float f; } v; v.u = ((unsigned)h) << 16;
  return v.f;
}
__device__ __forceinline__ void split2(float x, u16& h, u16& l) {
  h = f2bf(x);
  l = f2bf(x - bf2f(h));
}
__device__ __forceinline__ void async_cp16(const void* g, void* l) {
  __builtin_amdgcn_global_load_lds(
      (const __attribute__((address_space(1))) void*)g,
      (__attribute__((address_space(3))) void*)l, 16, 0, 0);
}

// ============================================================
// embed: x1[b,s,:] = emb[src[b,s]] + pos_enc[0,s,:]
// ============================================================
__global__ __launch_bounds__(256) void embed_kernel(
    const int* __restrict__ src, const float* __restrict__ emb,
    const float* __restrict__ pos, float* __restrict__ x1)
{
  int i4 = blockIdx.x * 256 + threadIdx.x;
  int bs = i4 >> 7, r4 = i4 & 127;
  int tok = src[bs];
  int s = bs & (kS - 1);
  float4 e = ((const float4*)emb)[(size_t)tok * 128 + r4];
  float4 p = ((const float4*)pos)[(size_t)s * 128 + r4];
  ((float4*)x1)[i4] = make_float4(e.x + p.x, e.y + p.y, e.z + p.z, e.w + p.w);
}

// ============================================================
// layernorm -> optional fp32 out + bf16 hi/lo out
// ============================================================
template<int WF32>
__global__ __launch_bounds__(256) void ln_kernel(
    const float* __restrict__ x, const float* __restrict__ sc,
    const float* __restrict__ bi, float* __restrict__ outf,
    u16* __restrict__ oh, u16* __restrict__ ol)
{
  int row = blockIdx.x * 4 + (threadIdx.x >> 6);
  int lane = threadIdx.x & 63;
  const float4* xr = (const float4*)(x + (size_t)row * kD);
  float4 v0 = xr[lane], v1 = xr[lane + 64];
  float sum = v0.x + v0.y + v0.z + v0.w + v1.x + v1.y + v1.z + v1.w;
  #pragma unroll
  for (int off = 1; off < 64; off <<= 1) sum += __shfl_xor(sum, off);
  float m = sum * (1.f / kD);
  float4 d0 = make_float4(v0.x - m, v0.y - m, v0.z - m, v0.w - m);
  float4 d1 = make_float4(v1.x - m, v1.y - m, v1.z - m, v1.w - m);
  float vs = d0.x*d0.x + d0.y*d0.y + d0.z*d0.z + d0.w*d0.w
           + d1.x*d1.x + d1.y*d1.y + d1.z*d1.z + d1.w*d1.w;
  #pragma unroll
  for (int off = 1; off < 64; off <<= 1) vs += __shfl_xor(vs, off);
  float rr = rsqrtf(vs * (1.f / kD) + 1e-5f);
  const float4* s4 = (const float4*)sc;
  const float4* b4 = (const float4*)bi;
  float4 s0 = s4[lane], s1 = s4[lane + 64], bb0 = b4[lane], bb1 = b4[lane + 64];
  float4 o0 = make_float4(d0.x*rr*s0.x + bb0.x, d0.y*rr*s0.y + bb0.y,
                          d0.z*rr*s0.z + bb0.z, d0.w*rr*s0.w + bb0.w);
  float4 o1 = make_float4(d1.x*rr*s1.x + bb1.x, d1.y*rr*s1.y + bb1.y,
                          d1.z*rr*s1.z + bb1.z, d1.w*rr*s1.w + bb1.w);
  if (WF32) {
    float4* op = (float4*)(outf + (size_t)row * kD);
    op[lane] = o0; op[lane + 64] = o1;
  }
  ushort4 h0, l0, h1, l1;
  split2(o0.x, h0.x, l0.x); split2(o0.y, h0.y, l0.y);
  split2(o0.z, h0.z, l0.z); split2(o0.w, h0.w, l0.w);
  split2(o1.x, h1.x, l1.x); split2(o1.y, h1.y, l1.y);
  split2(o1.z, h1.z, l1.z); split2(o1.w, h1.w, l1.w);
  ushort4* hp = (ushort4*)(oh + (size_t)row * kD);
  ushort4* lp = (ushort4*)(ol + (size_t)row * kD);
  hp[lane] = h0; hp[lane + 64] = h1;
  lp[lane] = l0; lp[lane + 64] = l1;
}

// ============================================================
// fp32 GEMM (kept for Wqk only -- exact bucketing numerics)
// ============================================================
constexpr int GBM = 128, GBN = 128, GBK = 16;

__global__ __launch_bounds__(256) void gemm_f32(
    const float* __restrict__ A, const float* __restrict__ Bw,
    float* __restrict__ C, int M, int N, int K)
{
  __shared__ float As[GBK][GBM];
  __shared__ float Bs[GBK][GBN];
  const int tid = threadIdx.x;
  const int tx = tid & 15, ty = tid >> 4;
  const int n0 = blockIdx.x * GBN, m0 = blockIdx.y * GBM;
  float acc[8][8] = {};
  for (int k0 = 0; k0 < K; k0 += GBK) {
    #pragma unroll
    for (int it = 0; it < 2; ++it) {
      int t = tid + it * 256;
      int row = t >> 2, c4 = (t & 3) << 2;
      float4 a4 = *(const float4*)&A[(size_t)(m0 + row) * K + k0 + c4];
      As[c4 + 0][row] = a4.x; As[c4 + 1][row] = a4.y;
      As[c4 + 2][row] = a4.z; As[c4 + 3][row] = a4.w;
    }
    #pragma unroll
    for (int it = 0; it < 2; ++it) {
      int t = tid + it * 256;
      int row = t >> 5, c4 = (t & 31) << 2;
      *(float4*)&Bs[row][c4] = *(const float4*)&Bw[(size_t)(k0 + row) * N + n0 + c4];
    }
    __syncthreads();
    #pragma unroll
    for (int kk = 0; kk < GBK; ++kk) {
      float4 a0 = *(float4*)&As[kk][ty * 8], a1 = *(float4*)&As[kk][ty * 8 + 4];
      float4 b0 = *(float4*)&Bs[kk][tx * 8], b1 = *(float4*)&Bs[kk][tx * 8 + 4];
      float av[8] = {a0.x, a0.y, a0.z, a0.w, a1.x, a1.y, a1.z, a1.w};
      float bv[8] = {b0.x, b0.y, b0.z, b0.w, b1.x, b1.y, b1.z, b1.w};
      #pragma unroll
      for (int i = 0; i < 8; ++i)
        #pragma unroll
        for (int j = 0; j < 8; ++j)
          acc[i][j] = fmaf(av[i], bv[j], acc[i][j]);
    }
    __syncthreads();
  }
  #pragma unroll
  for (int i = 0; i < 8; ++i) {
    size_t rowb = (size_t)(m0 + ty * 8 + i) * N + n0 + tx * 8;
    *(float4*)&C[rowb]     = make_float4(acc[i][0], acc[i][1], acc[i][2], acc[i][3]);
    *(float4*)&C[rowb + 4] = make_float4(acc[i][4], acc[i][5], acc[i][6], acc[i][7]);
  }
}

// ============================================================
// bf16 MFMA GEMM (m97 structure). A[M][K], B[N][K] bf16 (K contiguous).
// MT=4 -> 128x128 tile, MT=2 -> 64x64 tile. BK=32. 4 waves (2x2).
// SPLIT: A,B given as hi+lo; acc3 = h*h + h*l + l*h (~fp32 accuracy).
// Epilogue: C = resid? + sigmoid(gate[n])*act(acc + bias[n]); fp32 or bf16 hi/lo out.
// ============================================================
template<int MT, int SPLIT, int OBF>
__global__ __launch_bounds__(256) void gemm_mfma(
    const u16* __restrict__ Ah, const u16* __restrict__ Al,
    const u16* __restrict__ Bh, const u16* __restrict__ Bl,
    float* __restrict__ C, u16* __restrict__ Ch, u16* __restrict__ Cl,
    const float* __restrict__ bias, const float* __restrict__ resid,
    const float* __restrict__ gatev, int M, int N, int K, int relu)
{
  constexpr int BM = MT * 32;
  __shared__ alignas(16) u16 sAh[BM * 32];
  __shared__ alignas(16) u16 sBh[BM * 32];
  __shared__ alignas(16) u16 sAl[SPLIT ? BM * 32 : 8];
  __shared__ alignas(16) u16 sBl[SPLIT ? BM * 32 : 8];

  const int tid = threadIdx.x;
  const int w = tid >> 6, lane = tid & 63;
  const int wr = w >> 1, wc = w & 1;
  const int lrow = lane & 15, lko = (lane >> 4) * 8;
  const int wrow = wr * MT * 16, wcol = wc * MT * 16;
  const int m0 = blockIdx.y * BM, n0 = blockIdx.x * BM;

  f32x4 acc[MT][MT] = {};

  for (int k0 = 0; k0 < K; k0 += 32) {
    __syncthreads();
    #pragma unroll
    for (int it = 0; it < MT / 2; ++it) {
      int t = tid + it * 256;
      int row = t >> 2, ch = (t & 3) * 8;
      size_t ga = (size_t)(m0 + row) * K + k0 + ch;
      size_t gb = (size_t)(n0 + row) * K + k0 + ch;
      async_cp16(Ah + ga, &sAh[t * 8]);
      async_cp16(Bh + gb, &sBh[t * 8]);
      if (SPLIT) {
        async_cp16(Al + ga, &sAl[t * 8]);
        async_cp16(Bl + gb, &sBl[t * 8]);
      }
    }
    __syncthreads();

    bf16x8 aH[MT], bH[MT], aL[MT], bL[MT];
    #pragma unroll
    for (int f = 0; f < MT; ++f) {
      aH[f] = *(const bf16x8*)&sAh[(wrow + f * 16 + lrow) * 32 + lko];
      bH[f] = *(const bf16x8*)&sBh[(wcol + f * 16 + lrow) * 32 + lko];
      if (SPLIT) {
        aL[f] = *(const bf16x8*)&sAl[(wrow + f * 16 + lrow) * 32 + lko];
        bL[f] = *(const bf16x8*)&sBl[(wcol + f * 16 + lrow) * 32 + lko];
      }
    }
    #pragma unroll
    for (int fm = 0; fm < MT; ++fm)
      #pragma unroll
      for (int fn = 0; fn < MT; ++fn) {
        acc[fm][fn] = __builtin_amdgcn_mfma_f32_16x16x32_bf16(aH[fm], bH[fn], acc[fm][fn], 0, 0, 0);
        if (SPLIT) {
          acc[fm][fn] = __builtin_amdgcn_mfma_f32_16x16x32_bf16(aH[fm], bL[fn], acc[fm][fn], 0, 0, 0);
          acc[fm][fn] = __builtin_amdgcn_mfma_f32_16x16x32_bf16(aL[fm], bH[fn], acc[fm][fn], 0, 0, 0);
        }
      }
  }

  #pragma unroll
  for (int fm = 0; fm < MT; ++fm) {
    #pragma unroll
    for (int fn = 0; fn < MT; ++fn) {
      int row0 = m0 + wrow + fm * 16 + (lane >> 4) * 4;
      int col  = n0 + wcol + fn * 16 + lrow;
      float bv = bias ? bias[col] : 0.f;
      float gv = gatev ? 1.f / (1.f + __expf(-gatev[col])) : 1.f;
      #pragma unroll
      for (int i = 0; i < 4; ++i) {
        float vL = acc[fm][fn][i] + bv;
        if (relu) vL = fmaxf(vL, 0.f);
        vL *= gv;
        size_t idx = (size_t)(row0 + i) * N + col;
        if (resid) vL += resid[idx];
        if (OBF) {
          u16 h, l; split2(vL, h, l);
          Ch[idx] = h; Cl[idx] = l;
        } else {
          C[idx] = vL;
        }
      }
    }
  }
}

// ============================================================
// weight convert+transpose: W fp32 [K][N] -> bf16 hi(+lo) [N][K]
// ============================================================
template<int LO>
__global__ __launch_bounds__(256) void wconv(
    const float* __restrict__ W, u16* __restrict__ Th, u16* __restrict__ Tl,
    int K, int N)
{
  __shared__ float tile[64][65];
  const int n0 = blockIdx.x * 64, k0 = blockIdx.y * 64;
  const int t = threadIdx.x;
  const int tr = t >> 4, tc4 = (t & 15) * 4;
  #pragma unroll
  for (int i = 0; i < 4; ++i) {
    float4 v = *(const float4*)&W[(size_t)(k0 + tr + 16 * i) * N + n0 + tc4];
    tile[tr + 16 * i][tc4 + 0] = v.x; tile[tr + 16 * i][tc4 + 1] = v.y;
    tile[tr + 16 * i][tc4 + 2] = v.z; tile[tr + 16 * i][tc4 + 3] = v.w;
  }
  __syncthreads();
  #pragma unroll
  for (int i = 0; i < 4; ++i) {
    int n = tr + 16 * i;
    ushort4 h, l;
    split2(tile[tc4 + 0][n], h.x, l.x);
    split2(tile[tc4 + 1][n], h.y, l.y);
    split2(tile[tc4 + 2][n], h.z, l.z);
    split2(tile[tc4 + 3][n], h.w, l.w);
    *(ushort4*)&Th[(size_t)(n0 + n) * K + k0 + tc4] = h;
    if (LO) *(ushort4*)&Tl[(size_t)(n0 + n) * K + k0 + tc4] = l;
  }
}

// ============================================================
// LSH projections + bucket argmax (unchanged, fp32 qk)
// ============================================================
__global__ __launch_bounds__(256) void lsh_proj_kernel(
    const float* __restrict__ qk, const float* __restrict__ hashRl,
    int* __restrict__ buckets)
{
  __shared__ float shR[kNH * kDH * kNB2];
  const int bh = blockIdx.x, b = bh >> 3, h = bh & 7;
  const int tid = threadIdx.x;
  for (int i = tid; i < kNH * kDH * kNB2; i += 256) {
    int r = i >> 11, rem = i & 2047;
    shR[i] = hashRl[((size_t)(r * kH + h)) * 2048 + rem];
  }
  __syncthreads();
  const int s = blockIdx.y * 256 + tid;
  const float4* q4p = (const float4*)&qk[((size_t)(b * kS + s)) * kD + h * kDH];
  for (int rr = 0; rr < kNH; ++rr) {
    float acc[32] = {};
    const float4* h4 = (const float4*)&shR[rr * 2048];
    for (int d4 = 0; d4 < 16; ++d4) {
      float4 qv4 = q4p[d4];
      float qs[4] = {qv4.x, qv4.y, qv4.z, qv4.w};
      #pragma unroll
      for (int dd = 0; dd < 4; ++dd) {
        const float4* hh = &h4[(d4 * 4 + dd) * 8];
        float qv = qs[dd];
        #pragma unroll
        for (int n4 = 0; n4 < 8; ++n4) {
          float4 hv = hh[n4];
          acc[n4*4+0] = fmaf(qv, hv.x, acc[n4*4+0]);
          acc[n4*4+1] = fmaf(qv, hv.y, acc[n4*4+1]);
          acc[n4*4+2] = fmaf(qv, hv.z, acc[n4*4+2]);
          acc[n4*4+3] = fmaf(qv, hv.w, acc[n4*4+3]);
        }
      }
    }
    float best = acc[0]; int bi = 0;
    #pragma unroll
    for (int n = 1; n < 32; ++n) { if (acc[n] > best) { best = acc[n]; bi = n; } }
    #pragma unroll
    for (int n = 0; n < 32; ++n) { float t = -acc[n]; if (t > best) { best = t; bi = 32 + n; } }
    buckets[((size_t)(bh * kNH + rr)) * kS + s] = bi;
  }
}

// ============================================================
// stable counting sort by bucket (unchanged)
// ============================================================
__global__ __launch_bounds__(64) void sort_kernel(
    const int* __restrict__ buckets, int* __restrict__ perm)
{
  __shared__ int lb[kS];
  __shared__ int hist[64];
  __shared__ int offs[64];
  const int base = blockIdx.x * kS;
  const int tid = threadIdx.x;
  const int4* b4 = (const int4*)(buckets + base);
  for (int i = tid; i < kS / 4; i += 64) ((int4*)lb)[i] = b4[i];
  hist[tid] = 0;
  __syncthreads();
  for (int i = tid; i < kS; i += 64) atomicAdd(&hist[lb[i]], 1);
  __syncthreads();
  if (tid == 0) {
    int run = 0;
    for (int j = 0; j < 64; ++j) { offs[j] = run; run += hist[j]; }
  }
  __syncthreads();
  int off = offs[tid];
  for (int i = 0; i < kS; ++i)
    if (lb[i] == tid) perm[base + off++] = i;
}

// ============================================================
// chunk attention (unchanged, fp32)
// ============================================================
__device__ __forceinline__ int ssw(int q, int k) { return q * 128 + (k ^ (q & 31)); }

__global__ __launch_bounds__(256) void chunk_attn_kernel(
    const float* __restrict__ qk, const float* __restrict__ v,
    const int* __restrict__ perm, float* __restrict__ gout, int r)
{
  __shared__ float sm[16384];
  float* KT = sm;
  float* Vs = sm;
  float* Ss = sm + 8192;
  const int c = blockIdx.x, bh = blockIdx.y;
  const int b = bh >> 3, h = bh & 7;
  const int tid = threadIdx.x;
  const int permBase = (bh * kNH + r) * kS;

  #pragma unroll
  for (int it = 0; it < 8; ++it) {
    int task = tid + it * 256;
    int row = task >> 4, q4 = (task & 15) << 2;
    int srt = (row < 64) ? (c * 64 + row) : (((c + 63) & 63) * 64 + (row - 64));
    int orig = perm[permBase + srt];
    float4 kv = *(const float4*)&qk[((size_t)(b * kS + orig)) * kD + h * kDH + q4];
    KT[(q4 + 0) * 128 + row] = kv.x;
    KT[(q4 + 1) * 128 + row] = kv.y;
    KT[(q4 + 2) * 128 + row] = kv.z;
    KT[(q4 + 3) * 128 + row] = kv.w;
  }
  __syncthreads();

  const int tx = tid & 15, ty = tid >> 4;
  float accS[4][8] = {};
  #pragma unroll 8
  for (int d = 0; d < 64; ++d) {
    const float* Kd = &KT[d * 128];
    float qv[4];
    #pragma unroll
    for (int i = 0; i < 4; ++i) qv[i] = Kd[ty * 4 + i];
    float4 k0 = *(const float4*)&Kd[tx * 8];
    float4 k1 = *(const float4*)&Kd[tx * 8 + 4];
    float kv[8] = {k0.x, k0.y, k0.z, k0.w, k1.x, k1.y, k1.z, k1.w};
    #pragma unroll
    for (int i = 0; i < 4; ++i)
      #pragma unroll
      for (int j = 0; j < 8; ++j)
        accS[i][j] = fmaf(qv[i], kv[j], accS[i][j]);
  }
  #pragma unroll
  for (int i = 0; i < 4; ++i)
    #pragma unroll
    for (int j = 0; j < 8; ++j)
      Ss[ssw(ty * 4 + i, tx * 8 + j)] = accS[i][j] * 0.125f;
  __syncthreads();

  #pragma unroll
  for (int it = 0; it < 8; ++it) {
    int task = tid + it * 256;
    int row = task >> 4, q4 = (task & 15) << 2;
    int srt = (row < 64) ? (c * 64 + row) : (((c + 63) & 63) * 64 + (row - 64));
    int orig = perm[permBase + srt];
    float4 vv = *(const float4*)&v[((size_t)(b * kS + orig)) * kD + h * kDH + q4];
    *(float4*)&Vs[row * 64 + q4] = vv;
  }
  if (tid < 64) {
    int q = tid, qx = q & 31;
    float mxv = -1e30f;
    for (int k = 0; k < 128; ++k) mxv = fmaxf(mxv, Ss[q * 128 + (k ^ qx)]);
    float se = 0.f;
    for (int k = 0; k < 128; ++k) {
      float e = __expf(Ss[q * 128 + (k ^ qx)] - mxv);
      Ss[q * 128 + (k ^ qx)] = e; se += e;
    }
    float inv = 1.f / se;
    for (int k = 0; k < 128; ++k) Ss[q * 128 + (k ^ qx)] *= inv;
  }
  __syncthreads();

  float accO[4][4] = {};
  #pragma unroll 8
  for (int k = 0; k < 128; ++k) {
    float pv[4];
    #pragma unroll
    for (int i = 0; i < 4; ++i) pv[i] = Ss[ssw(ty * 4 + i, k)];
    float4 vr = *(const float4*)&Vs[k * 64 + tx * 4];
    float vw[4] = {vr.x, vr.y, vr.z, vr.w};
    #pragma unroll
    for (int i = 0; i < 4; ++i)
      #pragma unroll
      for (int j = 0; j < 4; ++j)
        accO[i][j] = fmaf(pv[i], vw[j], accO[i][j]);
  }
  #pragma unroll
  for (int i = 0; i < 4; ++i) {
    int q = ty * 4 + i;
    int orig = perm[permBase + c * 64 + q];
    float* gp = &gout[((size_t)(bh * kS + orig)) * kDH + tx * 4];
    float4 g4 = *(float4*)gp;
    g4.x += accO[i][0]; g4.y += accO[i][1]; g4.z += accO[i][2]; g4.w += accO[i][3];
    *(float4*)gp = g4;
  }
}

// ============================================================
// local attention + gate + merge; writes bf16 hi/lo o (head-concat layout)
// ============================================================
__global__ __launch_bounds__(256) void combine_kernel(
    const float* __restrict__ qk, const float* __restrict__ v,
    const float* __restrict__ gout, const float* __restrict__ gate_w,
    u16* __restrict__ oh, u16* __restrict__ ol, float* __restrict__ reg_acc)
{
  const int bh = blockIdx.x, b = bh >> 3, h = bh & 7;
  const int s = blockIdx.y * 256 + threadIdx.x;
  const float4* qrow = (const float4*)&qk[((size_t)(b * kS + s)) * kD + h * kDH];
  float4 q4[16];
  #pragma unroll
  for (int i = 0; i < 16; ++i) q4[i] = qrow[i];

  const float4* gw4 = (const float4*)&gate_w[h * kDH];
  float gd = 0.f;
  #pragma unroll
  for (int i = 0; i < 16; ++i) {
    float4 g = gw4[i];
    gd += q4[i].x * g.x + q4[i].y * g.y + q4[i].z * g.z + q4[i].w * g.w;
  }
  float gate = 1.f / (1.f + __expf(-gd));

  float p[9]; float mx = -1e30f;
  #pragma unroll
  for (int w = 0; w < 9; ++w) {
    int ss = s + w - 4;
    float scv = -1e9f;
    if (ss >= 0 && ss < kS) {
      const float4* kr = (const float4*)&qk[((size_t)(b * kS + ss)) * kD + h * kDH];
      float a = 0.f;
      #pragma unroll
      for (int i = 0; i < 16; ++i) {
        float4 kk = kr[i];
        a += q4[i].x * kk.x + q4[i].y * kk.y + q4[i].z * kk.z + q4[i].w * kk.w;
      }
      scv = a * 0.125f;
    }
    p[w] = scv; mx = fmaxf(mx, scv);
  }
  float se = 0.f;
  #pragma unroll
  for (int w = 0; w < 9; ++w) { p[w] = __expf(p[w] - mx); se += p[w]; }
  float inv = 1.f / se;

  const float4* g4p = (const float4*)&gout[((size_t)(bh * kS + s)) * kDH];
  u16* ohp = oh + ((size_t)(b * kS + s)) * kD + h * kDH;
  u16* olp = ol + ((size_t)(b * kS + s)) * kD + h * kDH;
  float og = gate, olw = 1.f - gate;
  #pragma unroll
  for (int d4 = 0; d4 < 16; ++d4) {
    float ax = 0.f, ay = 0.f, az = 0.f, aw = 0.f;
    #pragma unroll
    for (int w = 0; w < 9; ++w) {
      int ss = s + w - 4;
      if (ss >= 0 && ss < kS) {
        const float4* vr = (const float4*)&v[((size_t)(b * kS + ss)) * kD + h * kDH];
        float4 vv = vr[d4];
        ax = fmaf(p[w], vv.x, ax); ay = fmaf(p[w], vv.y, ay);
        az = fmaf(p[w], vv.z, az); aw = fmaf(p[w], vv.w, aw);
      }
    }
    float4 gg = g4p[d4];
    float ox = og * (gg.x * 0.25f) + olw * (ax * inv);
    float oy = og * (gg.y * 0.25f) + olw * (ay * inv);
    float oz = og * (gg.z * 0.25f) + olw * (az * inv);
    float ow = og * (gg.w * 0.25f) + olw * (aw * inv);
    ushort4 hh, ll;
    split2(ox, hh.x, ll.x); split2(oy, hh.y, ll.y);
    split2(oz, hh.z, ll.z); split2(ow, hh.w, ll.w);
    *(ushort4*)&ohp[d4 * 4] = hh;
    *(ushort4*)&olp[d4 * 4] = ll;
  }
  float rg = gate * (1.f - gate);
  #pragma unroll
  for (int off = 1; off < 64; off <<= 1) rg += __shfl_xor(rg, off);
  __shared__ float wsum[4];
  if ((threadIdx.x & 63) == 0) wsum[threadIdx.x >> 6] = rg;
  __syncthreads();
  if (threadIdx.x == 0) atomicAdd(reg_acc, wsum[0] + wsum[1] + wsum[2] + wsum[3]);
}

// ============================================================
// out = (x1 + x2)/2 for first T tokens -> bf16 hi (compact B*T x D)
// ============================================================
__global__ __launch_bounds__(256) void avg_kernel(
    const float* __restrict__ x1, const float* __restrict__ x2,
    u16* __restrict__ out)
{
  int i4 = blockIdx.x * 256 + threadIdx.x;   // over B*T*D/4
  int bt = i4 >> 7, r4 = i4 & 127;
  int b = bt >> 11, t = bt & (kT - 1);
  size_t si = ((size_t)(b * kS + t)) * 128 + r4;
  float4 a = ((const float4*)x1)[si], c = ((const float4*)x2)[si];
  ushort4 h;
  h.x = f2bf(0.5f * (a.x + c.x)); h.y = f2bf(0.5f * (a.y + c.y));
  h.z = f2bf(0.5f * (a.z + c.z)); h.w = f2bf(0.5f * (a.w + c.w));
  ((ushort4*)out)[i4] = h;
}

__global__ void finalize_kernel(const float* __restrict__ reg, float* __restrict__ out) {
  if (threadIdx.x == 0) out[0] = reg[0] * (1.f / 65536.f);
}

// ============================================================
extern "C" void kernel_launch(void* const* d_in, const int* in_sizes, int n_in,
                              void* d_out, int out_size, void* d_ws, size_t ws_size,
                              hipStream_t stream)
{
  const int*   src   = (const int*)d_in[0];
  const float* emb   = (const float*)d_in[2];
  const float* pos   = (const float*)d_in[3];
  const float* alns  = (const float*)d_in[4];
  const float* alnb  = (const float*)d_in[5];
  const float* Wqk   = (const float*)d_in[6];
  const float* Wv    = (const float*)d_in[7];
  const float* Wo    = (const float*)d_in[8];
  const float* hashR = (const float*)d_in[9];
  const float* gatew = (const float*)d_in[10];
  const float* rg1   = (const float*)d_in[11];
  const float* rg2   = (const float*)d_in[12];
  const float* flns  = (const float*)d_in[13];
  const float* flnb  = (const float*)d_in[14];
  const float* W1    = (const float*)d_in[15];
  const float* b1    = (const float*)d_in[16];
  const float* W2    = (const float*)d_in[17];
  const float* b2    = (const float*)d_in[18];
  const float* outW  = (const float*)d_in[19];
  const float* outb  = (const float*)d_in[20];
  float* logits = (float*)d_out;

  constexpr size_t NBS = (size_t)kB * kS * kD;   // 4194304
  float* x1 = (float*)d_ws;
  float* x2 = x1 + NBS;
  float* qk = x2 + NBS;
  float* vv = qk + NBS;
  float* go = vv + NBS;                 // also xn (fp32) alias
  float* xn = go;
  u16* a_h  = (u16*)(go + NBS);         // bf16 activations hi
  u16* a_l  = a_h + NBS;                // bf16 activations lo
  float* reg = (float*)(a_l + NBS);
  // f1 (relu output) aliases qk region: 8MB hi + 8MB lo
  u16* f1_h = (u16*)qk;
  u16* f1_l = f1_h + NBS;
  // outW^T bf16 spans vv..go (32.8 MB <= 33.5 MB), used only at the end
  u16* outWt = (u16*)vv;
  // transient scratch carved from d_out (dead before final gemm writes logits)
  char* ob = (char*)d_out;
  u16* wt_h = (u16*)ob;                  // 512x512 bf16 = 0.5 MB
  u16* wt_l = (u16*)(ob + 524288);
  int* buckets = (int*)(ob + 1048576);   // 1 MB
  int* perm    = (int*)(ob + 2097152);   // 1 MB

  embed_kernel<<<4096, 256, 0, stream>>>(src, emb, pos, x1);
  hipMemsetAsync(x2, 0, NBS * sizeof(float), stream);
  hipMemsetAsync(reg, 0, sizeof(float), stream);

  const dim3 gQK(4, 64);                 // fp32 gemm: N=512/128, M=8192/128
  const dim3 gSm(8, 128);                // mfma MT=2: N=512/64, M=8192/64
  const dim3 gWc(8, 8);                  // wconv 512x512

  for (int l = 0; l < 2; ++l) {
    const size_t wOff = (size_t)l * kD * kD;
    ln_kernel<1><<<kB * kS / 4, 256, 0, stream>>>(x2, alns + l * kD, alnb + l * kD,
                                                  xn, a_h, a_l);
    gemm_f32<<<gQK, 256, 0, stream>>>(xn, Wqk + wOff, qk, kB * kS, kD, kD);
    wconv<1><<<gWc, 256, 0, stream>>>(Wv + wOff, wt_h, wt_l, kD, kD);
    gemm_mfma<2, 1, 0><<<gSm, 256, 0, stream>>>(a_h, a_l, wt_h, wt_l, vv, nullptr, nullptr,
                                                nullptr, nullptr, nullptr, kB * kS, kD, kD, 0);
    lsh_proj_kernel<<<dim3(kB * kH, kS / 256), 256, 0, stream>>>(
        qk, hashR + (size_t)l * kNH * kH * kDH * kNB2, buckets);
    sort_kernel<<<kB * kH * kNH, 64, 0, stream>>>(buckets, perm);
    hipMemsetAsync(go, 0, NBS * sizeof(float), stream);
    for (int r = 0; r < kNH; ++r)
      chunk_attn_kernel<<<dim3(kNC, kB * kH), 256, 0, stream>>>(qk, vv, perm, go, r);
    combine_kernel<<<dim3(kB * kH, kS / 256), 256, 0, stream>>>(
        qk, vv, go, gatew + l * kH * kDH, a_h, a_l, reg);
    wconv<1><<<gWc, 256, 0, stream>>>(Wo + wOff, wt_h, wt_l, kD, kD);
    gemm_mfma<2, 1, 0><<<gSm, 256, 0, stream>>>(a_h, a_l, wt_h, wt_l, x1, nullptr, nullptr,
                                                nullptr, x1, rg1 + l * kD, kB * kS, kD, kD, 0);
    ln_kernel<0><<<kB * kS / 4, 256, 0, stream>>>(x1, flns + l * kD, flnb + l * kD,
                                                  nullptr, a_h, a_l);
    wconv<1><<<gWc, 256, 0, stream>>>(W1 + wOff, wt_h, wt_l, kD, kD);
    gemm_mfma<2, 1, 1><<<gSm, 256, 0, stream>>>(a_h, a_l, wt_h, wt_l, nullptr, f1_h, f1_l,
                                                b1 + l * kD, nullptr, nullptr, kB * kS, kD, kD, 1);
    wconv<1><<<gWc, 256, 0, stream>>>(W2 + wOff, wt_h, wt_l, kD, kD);
    gemm_mfma<2, 1, 0><<<gSm, 256, 0, stream>>>(f1_h, f1_l, wt_h, wt_l, x2, nullptr, nullptr,
                                                b2 + l * kD, x2, rg2 + l * kD, kB * kS, kD, kD, 0);
  }
  avg_kernel<<<kB * kT * kD / 4 / 256, 256, 0, stream>>>(x1, x2, a_h);
  wconv<0><<<dim3(kV / 64, kD / 64), 256, 0, stream>>>(outW, outWt, nullptr, kD, kV);
  gemm_mfma<4, 0, 0><<<dim3(kV / 128, kB * kT / 128), 256, 0, stream>>>(
      a_h, nullptr, outWt, nullptr, logits, nullptr, nullptr,
      outb, nullptr, nullptr, kB * kT, kV, kD, 0);
  finalize_kernel<<<1, 1, 0, stream>>>(reg, logits + (size_t)kB * kT * kV);
}